// Round 2
// baseline (2056.592 us; speedup 1.0000x reference)
//
#include <hip/hip_runtime.h>
#include <cstdint>
#include <cstddef>

typedef __attribute__((ext_vector_type(4))) float f32x4;
typedef __attribute__((ext_vector_type(8))) short short8;
typedef __attribute__((ext_vector_type(4))) unsigned int u32x4;

static const int TS = 2048;      // sequence length
static const int DM = 2048;      // d_model
static const int NHEAD = 16, NKVH = 8, HDIM = 128;
static const int FFD = 8192;
static const int NVOC = 32000;

__device__ __forceinline__ unsigned short f2bf(float f){
  unsigned int u = __builtin_bit_cast(unsigned int, f);
  u += 0x7FFFu + ((u >> 16) & 1u);
  return (unsigned short)(u >> 16);
}
__device__ __forceinline__ float bf2f(short h){
  unsigned int u = ((unsigned int)(unsigned short)h) << 16;
  return __builtin_bit_cast(float, u);
}
__device__ __forceinline__ f32x4 mfma16(short8 a, short8 b, f32x4 c){
  return __builtin_amdgcn_mfma_f32_16x16x32_bf16(a, b, c, 0, 0, 0);
}
__device__ __forceinline__ void gload16(const void* g, void* l){
  __builtin_amdgcn_global_load_lds(
      (const __attribute__((address_space(1))) unsigned int*)g,
      (__attribute__((address_space(3))) unsigned int*)l, 16, 0, 0);
}

// ---------------- RoPE tables ----------------
__global__ void rope_tables_k(float* __restrict__ cosT, float* __restrict__ sinT){
  int idx = blockIdx.x * 256 + threadIdx.x;   // TS*64 entries
  int s = idx >> 6, j = idx & 63;
  float inv = exp2f(-(float)j * (13.287712379549449f / 64.0f)); // 10000^(-j/64)
  float ang = (float)s * inv;
  cosT[idx] = cosf(ang);
  sinT[idx] = sinf(ang);
}

// ---------------- embedding gather ----------------
__global__ void embed_k(const int* __restrict__ ids, const float* __restrict__ E,
                        float* __restrict__ h){
  int s = blockIdx.x, tid = threadIdx.x;
  long id = ids[s];
  const f32x4* src = (const f32x4*)(E + id * (long)DM);
  f32x4* dst = (f32x4*)(h + (long)s * DM);
  dst[tid] = src[tid];
  dst[tid + 256] = src[tid + 256];
}

// ---------------- RMSNorm (f32 in -> bf16 out) ----------------
__global__ void rmsnorm_k(const float* __restrict__ x, const float* __restrict__ w,
                          short* __restrict__ out){
  int s = blockIdx.x, tid = threadIdx.x;
  const float* row = x + (long)s * DM;
  f32x4 v0 = *(const f32x4*)&row[tid * 8];
  f32x4 v1 = *(const f32x4*)&row[tid * 8 + 4];
  float ss = v0[0]*v0[0] + v0[1]*v0[1] + v0[2]*v0[2] + v0[3]*v0[3]
           + v1[0]*v1[0] + v1[1]*v1[1] + v1[2]*v1[2] + v1[3]*v1[3];
  #pragma unroll
  for (int off = 32; off; off >>= 1) ss += __shfl_xor(ss, off);
  __shared__ float sred[4];
  int wave = tid >> 6, lane = tid & 63;
  if (lane == 0) sred[wave] = ss;
  __syncthreads();
  float tot = sred[0] + sred[1] + sred[2] + sred[3];
  float r = rsqrtf(tot * (1.0f / (float)DM) + 1e-5f);
  f32x4 w0 = *(const f32x4*)&w[tid * 8];
  f32x4 w1 = *(const f32x4*)&w[tid * 8 + 4];
  short8 o;
  #pragma unroll
  for (int j = 0; j < 4; j++) o[j] = (short)f2bf(v0[j] * r * w0[j]);
  #pragma unroll
  for (int j = 0; j < 4; j++) o[4 + j] = (short)f2bf(v1[j] * r * w1[j]);
  *(short8*)&out[(long)s * DM + tid * 8] = o;
}

// ---------------- weight transpose+convert: B[K][N] f32 -> Bt[N][K] bf16 ----------------
__global__ void transpose_k(const float* __restrict__ B, short* __restrict__ Bt,
                            int K, int N){
  __shared__ float t[64][65];
  int tid = threadIdx.x;
  int kb = blockIdx.y * 64, nb = blockIdx.x * 64;
  int r0 = tid >> 4, c4 = tid & 15;
  #pragma unroll
  for (int p = 0; p < 4; p++){
    int r = r0 + p * 16;
    f32x4 v = *(const f32x4*)&B[(long)(kb + r) * N + nb + c4 * 4];
    t[r][c4*4+0] = v[0]; t[r][c4*4+1] = v[1]; t[r][c4*4+2] = v[2]; t[r][c4*4+3] = v[3];
  }
  __syncthreads();
  int n0 = tid >> 3, k0 = (tid & 7) * 8;
  #pragma unroll
  for (int p = 0; p < 2; p++){
    int n = n0 + p * 32;
    short8 o;
    #pragma unroll
    for (int j = 0; j < 8; j++) o[j] = (short)f2bf(t[k0 + j][n]);
    *(short8*)&Bt[(long)(nb + n) * K + kb + k0] = o;
  }
}

// ---------------- V transpose: vb[s][kv*HD+d] -> vtb[kv][d][s] (bf16) ----------------
__global__ void vtrans_k(const short* __restrict__ vb, short* __restrict__ vtb){
  int s0 = blockIdx.x * 64, kv = blockIdx.y;
  int tid = threadIdx.x;
  int s = s0 + (tid & 63);
  int d0 = (tid >> 6) * 8;
  #pragma unroll
  for (int p = 0; p < 4; p++){
    int d = d0 + p * 32;
    short8 v = *(const short8*)&vb[(long)s * (NKVH * HDIM) + kv * HDIM + d];
    #pragma unroll
    for (int j = 0; j < 8; j++)
      vtb[(long)(kv * HDIM + d + j) * TS + s] = v[j];
  }
}

// ---------------- RoPE apply (in-place bf16) ----------------
__global__ void rope_apply_k(short* __restrict__ q, const float* __restrict__ cosT,
                             const float* __restrict__ sinT, int nh){
  int idx = blockIdx.x * 256 + threadIdx.x;  // TS*nh*64
  int j = idx & 63;
  int t = idx >> 6;
  int hh = t % nh;
  int s = t / nh;
  long base = ((long)s * nh + hh) * HDIM + j;
  float c = cosT[s * 64 + j], sn = sinT[s * 64 + j];
  float x1 = bf2f(q[base]), x2 = bf2f(q[base + 64]);
  q[base]      = (short)f2bf(x1 * c - x2 * sn);
  q[base + 64] = (short)f2bf(x2 * c + x1 * sn);
}

// ---------------- GEMM: C[M,N] = A[M,K](bf16) x Bt[N,K](bf16) ----------------
// EPI: 0 = f32 store, 1 = bf16 store, 2 = f32 residual add (Cf += acc),
//      3 = bf16 silu(acc), 4 = bf16 (bf2f(Xtra) * acc)
template<int EPI>
__global__ __launch_bounds__(256)
void gemm_bt(const short* __restrict__ A, const short* __restrict__ Bt,
             float* __restrict__ Cf, short* __restrict__ Cb,
             const short* __restrict__ Xtra, int N, int K){
  __shared__ short As[128 * 32];
  __shared__ short Bs[128 * 32];
  const int tid = threadIdx.x;
  const int wave = tid >> 6, lane = tid & 63;
  const int wr = wave >> 1, wc = wave & 1;
  const int mb = blockIdx.y, nb = blockIdx.x;

  const int srow = wave * 16 + (lane >> 2);
  const int scol = (lane & 3) * 8;
  const short* Ag0 = A + (long)(mb * 128 + srow) * K + scol;
  const short* Ag1 = Ag0 + 64 * (long)K;
  const short* Bg0 = Bt + (long)(nb * 128 + srow) * K + scol;
  const short* Bg1 = Bg0 + 64 * (long)K;
  short* AsL0 = &As[wave * 512];
  short* AsL1 = &As[2048 + wave * 512];
  short* BsL0 = &Bs[wave * 512];
  short* BsL1 = &Bs[2048 + wave * 512];

  f32x4 acc[4][4] = {};
  const int fr = lane & 15, fc = (lane >> 4) * 8;

  for (int kb = 0; kb < K; kb += 32){
    __syncthreads();
    gload16(Ag0 + kb, AsL0);
    gload16(Ag1 + kb, AsL1);
    gload16(Bg0 + kb, BsL0);
    gload16(Bg1 + kb, BsL1);
    __syncthreads();
    short8 a[4], b[4];
    #pragma unroll
    for (int m = 0; m < 4; m++) a[m] = *(const short8*)&As[(wr*64 + m*16 + fr)*32 + fc];
    #pragma unroll
    for (int n = 0; n < 4; n++) b[n] = *(const short8*)&Bs[(wc*64 + n*16 + fr)*32 + fc];
    #pragma unroll
    for (int m = 0; m < 4; m++)
      #pragma unroll
      for (int n = 0; n < 4; n++)
        acc[m][n] = mfma16(a[m], b[n], acc[m][n]);
  }

  const int rb = mb * 128 + wr * 64 + (lane >> 4) * 4;
  const int cb = nb * 128 + wc * 64 + (lane & 15);
  #pragma unroll
  for (int m = 0; m < 4; m++)
    #pragma unroll
    for (int n = 0; n < 4; n++)
      #pragma unroll
      for (int i = 0; i < 4; i++){
        long idx = (long)(rb + m * 16 + i) * N + (cb + n * 16);
        float v = acc[m][n][i];
        if constexpr (EPI == 0) Cf[idx] = v;
        else if constexpr (EPI == 1) Cb[idx] = (short)f2bf(v);
        else if constexpr (EPI == 2) Cf[idx] += v;
        else if constexpr (EPI == 3){
          float sg = 1.0f / (1.0f + __expf(-v));
          Cb[idx] = (short)f2bf(v * sg);
        } else {
          float g = bf2f(Xtra[idx]);
          Cb[idx] = (short)f2bf(g * v);
        }
      }
}

// ---------------- flash attention ----------------
// grid: (TS/64, NHEAD); 256 threads (4 waves, 16 q-rows each)
__device__ __forceinline__ int qoff(int r, int cB){ return r * 256 + (cB ^ ((r & 7) << 4)); }
__device__ __forceinline__ int voff(int d, int cB){ return d * 128 + (cB ^ ((d & 7) << 4)); }
__device__ __forceinline__ int poff(int r, int cB){ return r * 128 + (cB ^ ((r & 7) << 4)); }

__global__ __launch_bounds__(256)
void attn_k(const short* __restrict__ qb, const short* __restrict__ kb,
            const short* __restrict__ vtb, short* __restrict__ ob){
  __shared__ short Qs[64 * 128];
  __shared__ short Ks[64 * 128];
  __shared__ short Vt[128 * 64];
  __shared__ short Ps[64 * 64];
  const int tid = threadIdx.x, wave = tid >> 6, lane = tid & 63;
  const int qt = blockIdx.x, head = blockIdx.y, kvh = head >> 1;
  const float scale = 0.08838834764831845f;  // 1/sqrt(128)

  // stage Q (once)
  {
    int r0 = tid >> 4, c16 = tid & 15;
    #pragma unroll
    for (int p = 0; p < 4; p++){
      int r = r0 + p * 16;
      u32x4 v = *(const u32x4*)&qb[(long)(qt * 64 + r) * DM + head * HDIM + c16 * 8];
      *(u32x4*)((char*)Qs + qoff(r, c16 * 16)) = v;
    }
  }

  float mrun[4] = {-1e30f, -1e30f, -1e30f, -1e30f};
  float lrun[4] = {0.f, 0.f, 0.f, 0.f};
  f32x4 accO[8] = {};

  for (int kt = 0; kt <= qt; kt++){
    __syncthreads();
    {
      int r0 = tid >> 4, c16 = tid & 15;
      #pragma unroll
      for (int p = 0; p < 4; p++){
        int r = r0 + p * 16;
        u32x4 v = *(const u32x4*)&kb[(long)(kt * 64 + r) * (NKVH * HDIM) + kvh * HDIM + c16 * 8];
        *(u32x4*)((char*)Ks + qoff(r, c16 * 16)) = v;
      }
      int vr0 = tid >> 3, vc = tid & 7;
      #pragma unroll
      for (int p = 0; p < 4; p++){
        int d = vr0 + p * 32;
        u32x4 v = *(const u32x4*)&vtb[(long)(kvh * HDIM + d) * TS + kt * 64 + vc * 8];
        *(u32x4*)((char*)Vt + voff(d, vc * 16)) = v;
      }
    }
    __syncthreads();

    // QK^T : wave's 16 q-rows x 64 keys
    f32x4 sacc[4] = {};
    #pragma unroll
    for (int k4 = 0; k4 < 4; k4++){
      short8 a = *(const short8*)((const char*)Qs +
                   qoff(wave * 16 + (lane & 15), k4 * 64 + (lane >> 4) * 16));
      #pragma unroll
      for (int n = 0; n < 4; n++){
        short8 b = *(const short8*)((const char*)Ks +
                     qoff(n * 16 + (lane & 15), k4 * 64 + (lane >> 4) * 16));
        sacc[n] = mfma16(a, b, sacc[n]);
      }
    }

    // scale + causal mask + online softmax
    const bool diag = (kt == qt);
    float mt[4] = {-1e30f, -1e30f, -1e30f, -1e30f};
    #pragma unroll
    for (int n = 0; n < 4; n++)
      #pragma unroll
      for (int i = 0; i < 4; i++){
        float v = sacc[n][i] * scale;
        if (diag){
          int r = (lane >> 4) * 4 + i + wave * 16;
          int c = n * 16 + (lane & 15);
          if (c > r) v = -1e30f;
        }
        sacc[n][i] = v;
        mt[i] = fmaxf(mt[i], v);
      }
    #pragma unroll
    for (int off = 1; off < 16; off <<= 1)
      #pragma unroll
      for (int i = 0; i < 4; i++) mt[i] = fmaxf(mt[i], __shfl_xor(mt[i], off));
    float alpha[4], rsum[4];
    #pragma unroll
    for (int i = 0; i < 4; i++){
      float mn = fmaxf(mrun[i], mt[i]);
      alpha[i] = __expf(mrun[i] - mn);
      mrun[i] = mn;
      rsum[i] = 0.f;
    }
    #pragma unroll
    for (int n = 0; n < 4; n++)
      #pragma unroll
      for (int i = 0; i < 4; i++){
        float p = __expf(sacc[n][i] - mrun[i]);
        sacc[n][i] = p;
        rsum[i] += p;
      }
    #pragma unroll
    for (int off = 1; off < 16; off <<= 1)
      #pragma unroll
      for (int i = 0; i < 4; i++) rsum[i] += __shfl_xor(rsum[i], off);
    #pragma unroll
    for (int i = 0; i < 4; i++) lrun[i] = lrun[i] * alpha[i] + rsum[i];

    // write P (own wave rows only -> no cross-wave barrier needed)
    #pragma unroll
    for (int n = 0; n < 4; n++)
      #pragma unroll
      for (int i = 0; i < 4; i++){
        int r = wave * 16 + (lane >> 4) * 4 + i;
        int c = n * 16 + (lane & 15);
        *(short*)((char*)Ps + poff(r, c * 2)) = (short)f2bf(sacc[n][i]);
      }

    // rescale O, then PV
    #pragma unroll
    for (int n = 0; n < 8; n++)
      #pragma unroll
      for (int i = 0; i < 4; i++) accO[n][i] *= alpha[i];
    #pragma unroll
    for (int ks = 0; ks < 2; ks++){
      short8 a = *(const short8*)((const char*)Ps +
                   poff(wave * 16 + (lane & 15), ks * 64 + (lane >> 4) * 16));
      #pragma unroll
      for (int n = 0; n < 8; n++){
        short8 b = *(const short8*)((const char*)Vt +
                     voff(n * 16 + (lane & 15), ks * 64 + (lane >> 4) * 16));
        accO[n] = mfma16(a, b, accO[n]);
      }
    }
  }

  // epilogue: O /= l, write bf16
  #pragma unroll
  for (int i = 0; i < 4; i++){
    float inv = 1.0f / lrun[i];
    int r = qt * 64 + wave * 16 + (lane >> 4) * 4 + i;
    #pragma unroll
    for (int n = 0; n < 8; n++){
      int c = head * HDIM + n * 16 + (lane & 15);
      ob[(long)r * DM + c] = (short)f2bf(accO[n][i] * inv);
    }
  }
}

// ---------------- host ----------------
extern "C" void kernel_launch(void* const* d_in, const int* in_sizes, int n_in,
                              void* d_out, int out_size, void* d_ws, size_t ws_size,
                              hipStream_t stream){
  (void)in_sizes; (void)n_in; (void)out_size; (void)ws_size;
  const int*   ids = (const int*)d_in[0];
  const float* E   = (const float*)d_in[1];
  const float* Wq  = (const float*)d_in[2];
  const float* Wk  = (const float*)d_in[3];
  const float* Wv  = (const float*)d_in[4];
  const float* Wo  = (const float*)d_in[5];
  const float* Wg  = (const float*)d_in[6];
  const float* Wu  = (const float*)d_in[7];
  const float* Wd  = (const float*)d_in[8];
  const float* nA  = (const float*)d_in[9];
  const float* nM  = (const float*)d_in[10];
  const float* nF  = (const float*)d_in[11];
  const float* LMH = (const float*)d_in[12];
  float* out = (float*)d_out;

  char* ws = (char*)d_ws;
  size_t off = 0;
  auto alloc = [&](size_t bytes){ void* p = ws + off; off += (bytes + 255) & ~(size_t)255; return p; };
  float* h    = (float*)alloc((size_t)TS * DM * 4);
  short* xb   = (short*)alloc((size_t)TS * DM * 2);
  short* qbuf = (short*)alloc((size_t)TS * DM * 2);
  short* kbuf = (short*)alloc((size_t)TS * NKVH * HDIM * 2);
  short* vbuf = (short*)alloc((size_t)TS * NKVH * HDIM * 2);
  short* vtb  = (short*)alloc((size_t)NKVH * HDIM * TS * 2);
  short* obuf = (short*)alloc((size_t)TS * DM * 2);
  short* sg   = (short*)alloc((size_t)TS * FFD * 2);
  short* actb = (short*)alloc((size_t)TS * FFD * 2);
  float* cosT = (float*)alloc((size_t)TS * 64 * 4);
  float* sinT = (float*)alloc((size_t)TS * 64 * 4);
  short* wT   = (short*)alloc((size_t)NVOC * DM * 2);

  rope_tables_k<<<512, 256, 0, stream>>>(cosT, sinT);
  embed_k<<<TS, 256, 0, stream>>>(ids, E, h);

  for (int l = 0; l < 2; l++){
    rmsnorm_k<<<TS, 256, 0, stream>>>(h, nA + (size_t)l * DM, xb);
    // Q = x @ Wq[l]
    transpose_k<<<dim3(32, 32), 256, 0, stream>>>(Wq + (size_t)l * DM * DM, wT, DM, DM);
    gemm_bt<1><<<dim3(16, 16), 256, 0, stream>>>(xb, wT, nullptr, qbuf, nullptr, DM, DM);
    // K
    transpose_k<<<dim3(16, 32), 256, 0, stream>>>(Wk + (size_t)l * DM * 1024, wT, DM, 1024);
    gemm_bt<1><<<dim3(8, 16), 256, 0, stream>>>(xb, wT, nullptr, kbuf, nullptr, 1024, DM);
    // V
    transpose_k<<<dim3(16, 32), 256, 0, stream>>>(Wv + (size_t)l * DM * 1024, wT, DM, 1024);
    gemm_bt<1><<<dim3(8, 16), 256, 0, stream>>>(xb, wT, nullptr, vbuf, nullptr, 1024, DM);
    // RoPE (in place on bf16), V transpose
    rope_apply_k<<<8192, 256, 0, stream>>>(qbuf, cosT, sinT, NHEAD);
    rope_apply_k<<<4096, 256, 0, stream>>>(kbuf, cosT, sinT, NKVH);
    vtrans_k<<<dim3(32, 8), 256, 0, stream>>>(vbuf, vtb);
    // attention
    attn_k<<<dim3(32, 16), 256, 0, stream>>>(qbuf, kbuf, vtb, obuf);
    // h += o @ Wo[l]
    transpose_k<<<dim3(32, 32), 256, 0, stream>>>(Wo + (size_t)l * DM * DM, wT, DM, DM);
    gemm_bt<2><<<dim3(16, 16), 256, 0, stream>>>(obuf, wT, h, nullptr, nullptr, DM, DM);
    // MLP
    rmsnorm_k<<<TS, 256, 0, stream>>>(h, nM + (size_t)l * DM, xb);
    transpose_k<<<dim3(128, 32), 256, 0, stream>>>(Wg + (size_t)l * DM * FFD, wT, DM, FFD);
    gemm_bt<3><<<dim3(64, 16), 256, 0, stream>>>(xb, wT, nullptr, sg, nullptr, FFD, DM);
    transpose_k<<<dim3(128, 32), 256, 0, stream>>>(Wu + (size_t)l * DM * FFD, wT, DM, FFD);
    gemm_bt<4><<<dim3(64, 16), 256, 0, stream>>>(xb, wT, nullptr, actb, sg, FFD, DM);
    transpose_k<<<dim3(32, 128), 256, 0, stream>>>(Wd + (size_t)l * FFD * DM, wT, FFD, DM);
    gemm_bt<2><<<dim3(16, 16), 256, 0, stream>>>(actb, wT, h, nullptr, nullptr, DM, FFD);
  }

  rmsnorm_k<<<TS, 256, 0, stream>>>(h, nF, xb);
  transpose_k<<<dim3(500, 32), 256, 0, stream>>>(LMH, wT, DM, NVOC);
  gemm_bt<0><<<dim3(250, 16), 256, 0, stream>>>(xb, wT, out, nullptr, nullptr, NVOC, DM);
}